// Round 1
// baseline (324.447 us; speedup 1.0000x reference)
//
#include <hip/hip_runtime.h>
#include <hip/hip_bf16.h>

// Problem constants (B=64, T=2048, D=512, U=512)
#define BB 64
#define TT 2048
#define DD 512
#define UU 512
#define CTX_ELEMS (BB * DD)          // 32768, context region of d_out
#define ATTN_OFF  CTX_ELEMS          // attention region offset in d_out

typedef __bf16 bf16x8 __attribute__((ext_vector_type(8)));
typedef float  f32x4  __attribute__((ext_vector_type(4)));
typedef unsigned int u32;

#define GLOBAL_AS __attribute__((address_space(1)))
#define LDS_AS    __attribute__((address_space(3)))

__device__ __forceinline__ unsigned short f2bf(float f) {
    union { float f; unsigned u; } x; x.f = f;
    unsigned r = x.u + 0x7fffu + ((x.u >> 16) & 1u);   // RNE
    return (unsigned short)(r >> 16);
}

// ---------------------------------------------------------------------------
// Kernel 1: W1 [D][U] f32  ->  W1T [U][D] bf16 (in ws)
// ---------------------------------------------------------------------------
__global__ void k_w1t(const float* __restrict__ W1, unsigned short* __restrict__ W1T) {
    int gid = blockIdx.x * 256 + threadIdx.x;
    int idx = gid * 4;                 // over U*D = 262144
    int u = idx >> 9;                  // / 512
    int d0 = idx & 511;
    ushort4 pk;
    pk.x = f2bf(W1[(size_t)(d0 + 0) * UU + u]);
    pk.y = f2bf(W1[(size_t)(d0 + 1) * UU + u]);
    pk.z = f2bf(W1[(size_t)(d0 + 2) * UU + u]);
    pk.w = f2bf(W1[(size_t)(d0 + 3) * UU + u]);
    *(ushort4*)(W1T + (size_t)u * DD + d0) = pk;
}

// ---------------------------------------------------------------------------
// Kernel 2: phc[b][u] = b1[u] + b2[u] + hidden[b,:] @ W2[:,u]   (in ws)
// ---------------------------------------------------------------------------
__global__ void k_phc(const float* __restrict__ hidden, const float* __restrict__ W2,
                      const float* __restrict__ b1, const float* __restrict__ b2,
                      float* __restrict__ phc) {
    const int b = blockIdx.x;
    const int u = threadIdx.x;         // 512 threads
    const float* h = hidden + (size_t)b * DD;
    float acc = b1[u] + b2[u];
    #pragma unroll 8
    for (int d = 0; d < DD; ++d)
        acc += h[d] * W2[(size_t)d * UU + u];
    phc[(size_t)b * UU + u] = acc;
}

// ---------------------------------------------------------------------------
// Kernel 3: fused score GEMM.
//   For 64 rows m (one block): z[m][u] = feat[m,:] @ W1[:,u] + phc[b][u]
//   score[m] = sum_u tanh(z[m][u]) * V[u]   -> d_out[ATTN_OFF + m]
// Tile: BM=64 x BN=512(full U) x BK=32, 8 waves (each 64 m x 64 n),
// mfma_f32_16x16x32_bf16.
// ---------------------------------------------------------------------------
__launch_bounds__(512, 2)
__global__ void k_score(const float* __restrict__ feat,
                        const unsigned short* __restrict__ W1T,
                        const float* __restrict__ phc,
                        const float* __restrict__ V,
                        float* __restrict__ dout) {
    __shared__ unsigned short sA[64 * 32];    // [m][k] bf16, 4 KB
    __shared__ unsigned short sB[512 * 32];   // [n][k] bf16, 32 KB
    __shared__ float sRed[8][64];

    const int tid  = threadIdx.x;
    const int lane = tid & 63;
    const int w    = tid >> 6;                // wave 0..7 -> n range [w*64, w*64+64)
    const int m0   = blockIdx.x * 64;
    const int b    = m0 >> 11;                // / T (64 | 2048 so no straddle)

    f32x4 acc[4][4];
    #pragma unroll
    for (int i = 0; i < 4; ++i)
        #pragma unroll
        for (int j = 0; j < 4; ++j)
            acc[i][j] = (f32x4){0.f, 0.f, 0.f, 0.f};

    const int r  = tid >> 3;                  // staging row 0..63
    const int c4 = (tid & 7) * 4;             // staging col (4 floats)
    const float* fsrc = feat + (size_t)(m0 + r) * DD + c4;

    for (int kt = 0; kt < 16; ++kt) {
        const int k0 = kt * 32;

        // B tile: W1T rows [0,512) cols [k0,k0+32) -> sB, direct global->LDS
        #pragma unroll
        for (int p = 0; p < 4; ++p) {
            int i = p * 512 + tid;
            const char* src = (const char*)W1T + (size_t)(i >> 2) * (DD * 2) + k0 * 2 + (i & 3) * 16;
            char* dst = (char*)sB + (size_t)(p * 512 + (tid & ~63)) * 16;  // wave-uniform base
            __builtin_amdgcn_global_load_lds((const GLOBAL_AS u32*)src, (LDS_AS u32*)dst, 16, 0, 0);
        }
        // A tile: feat rows [m0,m0+64) cols [k0,k0+32) f32 -> bf16 -> sA
        {
            float4 fv = *(const float4*)(fsrc + k0);
            ushort4 pk;
            pk.x = f2bf(fv.x); pk.y = f2bf(fv.y); pk.z = f2bf(fv.z); pk.w = f2bf(fv.w);
            *(ushort4*)(sA + r * 32 + c4) = pk;
        }
        __syncthreads();   // drains vmcnt (global_load_lds) + lgkmcnt

        bf16x8 af[4], bfr[4];
        #pragma unroll
        for (int ms = 0; ms < 4; ++ms)
            af[ms] = *(const bf16x8*)((const char*)sA + (size_t)(ms * 16 + (lane & 15)) * 64 + (lane >> 4) * 16);
        #pragma unroll
        for (int ns = 0; ns < 4; ++ns)
            bfr[ns] = *(const bf16x8*)((const char*)sB + (size_t)(w * 64 + ns * 16 + (lane & 15)) * 64 + (lane >> 4) * 16);
        #pragma unroll
        for (int ms = 0; ms < 4; ++ms)
            #pragma unroll
            for (int ns = 0; ns < 4; ++ns)
                acc[ms][ns] = __builtin_amdgcn_mfma_f32_16x16x32_bf16(af[ms], bfr[ns], acc[ms][ns], 0, 0, 0);
        __syncthreads();
    }

    // Epilogue: z = acc + phc;  partial score = sum_n tanh(z) * V[n]
    // C layout (m89-verified): col(n) = lane&15, row(m) = (lane>>4)*4 + reg
    float pc[4], vv[4];
    #pragma unroll
    for (int ns = 0; ns < 4; ++ns) {
        int u = w * 64 + ns * 16 + (lane & 15);
        pc[ns] = phc[(size_t)b * UU + u];
        vv[ns] = V[u];
    }
    float pr[4][4];
    #pragma unroll
    for (int ms = 0; ms < 4; ++ms)
        #pragma unroll
        for (int rg = 0; rg < 4; ++rg) {
            float s = 0.f;
            #pragma unroll
            for (int ns = 0; ns < 4; ++ns)
                s += tanhf(acc[ms][ns][rg] + pc[ns]) * vv[ns];
            pr[ms][rg] = s;
        }
    // reduce across the 16 lanes sharing a row-group (xor bits 0..3)
    #pragma unroll
    for (int off = 1; off < 16; off <<= 1)
        #pragma unroll
        for (int ms = 0; ms < 4; ++ms)
            #pragma unroll
            for (int rg = 0; rg < 4; ++rg)
                pr[ms][rg] += __shfl_xor(pr[ms][rg], off, 64);
    // lanes (lane&15)==0 hold full sums; write 16 m-values each (static idx)
    if ((lane & 15) == 0) {
        int rowg = lane >> 4;
        #pragma unroll
        for (int ms = 0; ms < 4; ++ms)
            #pragma unroll
            for (int rg = 0; rg < 4; ++rg)
                sRed[w][ms * 16 + rowg * 4 + rg] = pr[ms][rg];
    }
    __syncthreads();
    if (tid < 64) {
        float s = 0.f;
        #pragma unroll
        for (int ww = 0; ww < 8; ++ww) s += sRed[ww][tid];
        dout[ATTN_OFF + m0 + tid] = s;
    }
}

// ---------------------------------------------------------------------------
// Kernel 4: softmax over T per batch, in place in d_out attn region.
// ---------------------------------------------------------------------------
__global__ void k_softmax(float* __restrict__ dout) {
    const int b = blockIdx.x, tid = threadIdx.x;   // 256 threads
    float* sc = dout + ATTN_OFF + (size_t)b * TT;
    float v[8];
    float mx = -3.4e38f;
    #pragma unroll
    for (int i = 0; i < 8; ++i) { v[i] = sc[tid + 256 * i]; mx = fmaxf(mx, v[i]); }
    __shared__ float red[256];
    red[tid] = mx; __syncthreads();
    for (int s = 128; s >= 1; s >>= 1) {
        if (tid < s) red[tid] = fmaxf(red[tid], red[tid + s]);
        __syncthreads();
    }
    mx = red[0]; __syncthreads();
    float sum = 0.f;
    #pragma unroll
    for (int i = 0; i < 8; ++i) { v[i] = expf(v[i] - mx); sum += v[i]; }
    red[tid] = sum; __syncthreads();
    for (int s = 128; s >= 1; s >>= 1) {
        if (tid < s) red[tid] += red[tid + s];
        __syncthreads();
    }
    float inv = 1.0f / red[0];
    #pragma unroll
    for (int i = 0; i < 8; ++i) sc[tid + 256 * i] = v[i] * inv;
}

// ---------------------------------------------------------------------------
// Kernel 5: context[b][d] = sum_t w[b][t] * feat[b][t][d]
// grid (64, 8); block 256 = 64 d-lanes x 4 t-subgroups. No atomics.
// ---------------------------------------------------------------------------
__global__ void k_context(const float* __restrict__ feat, float* __restrict__ dout) {
    const int b = blockIdx.x, dc = blockIdx.y;
    const int tx = threadIdx.x & 63, ty = threadIdx.x >> 6;  // ty 0..3
    const int d = dc * 64 + tx;
    const float* wgt = dout + ATTN_OFF + (size_t)b * TT;
    const float* f = feat + (size_t)b * TT * DD + d;
    float acc = 0.f;
    #pragma unroll 4
    for (int i = 0; i < TT / 4; ++i) {
        int t = i * 4 + ty;
        acc += wgt[t] * f[(size_t)t * DD];
    }
    __shared__ float red[4][64];
    red[ty][tx] = acc; __syncthreads();
    if (ty == 0)
        dout[(size_t)b * DD + d] = red[0][tx] + red[1][tx] + red[2][tx] + red[3][tx];
}

// ---------------------------------------------------------------------------
extern "C" void kernel_launch(void* const* d_in, const int* in_sizes, int n_in,
                              void* d_out, int out_size, void* d_ws, size_t ws_size,
                              hipStream_t stream) {
    (void)in_sizes; (void)n_in; (void)out_size; (void)ws_size;
    const float* feat   = (const float*)d_in[0];
    const float* hidden = (const float*)d_in[1];
    const float* W1     = (const float*)d_in[2];
    const float* b1     = (const float*)d_in[3];
    const float* W2     = (const float*)d_in[4];
    const float* b2     = (const float*)d_in[5];
    const float* V      = (const float*)d_in[6];
    // d_in[7] = bV : additive constant on scores -> softmax-invariant, unused.

    // ws layout: [0, 512KB) W1T bf16 [U][D]; [512KB, 640KB) phc f32 [B][U]
    unsigned short* W1T = (unsigned short*)d_ws;
    float* phc = (float*)((char*)d_ws + 512 * 1024);
    float* out = (float*)d_out;

    hipLaunchKernelGGL(k_w1t,     dim3(256),    dim3(256), 0, stream, W1, W1T);
    hipLaunchKernelGGL(k_phc,     dim3(64),     dim3(512), 0, stream, hidden, W2, b1, b2, phc);
    hipLaunchKernelGGL(k_score,   dim3(2048),   dim3(512), 0, stream, feat, W1T, phc, V, out);
    hipLaunchKernelGGL(k_softmax, dim3(64),     dim3(256), 0, stream, out);
    hipLaunchKernelGGL(k_context, dim3(64, 8),  dim3(256), 0, stream, feat, out);
}

// Round 2
// 195.969 us; speedup vs baseline: 1.6556x; 1.6556x over previous
//
#include <hip/hip_runtime.h>
#include <hip/hip_bf16.h>

// Problem constants (B=64, T=2048, D=512, U=512)
#define BB 64
#define TT 2048
#define DD 512
#define UU 512
#define MM (BB * TT)                 // 131072 rows
#define CTX_ELEMS (BB * DD)          // context region of d_out
#define ATTN_OFF  CTX_ELEMS          // attention region offset in d_out

typedef __bf16 bf16x8 __attribute__((ext_vector_type(8)));
typedef float  f32x4  __attribute__((ext_vector_type(4)));
typedef unsigned short u16x8 __attribute__((ext_vector_type(8)));
typedef unsigned int u32;

#define GLOBAL_AS __attribute__((address_space(1)))
#define LDS_AS    __attribute__((address_space(3)))

__device__ __forceinline__ unsigned short f2bf(float f) {
    union { float f; unsigned u; } x; x.f = f;
    unsigned r = x.u + 0x7fffu + ((x.u >> 16) & 1u);   // RNE
    return (unsigned short)(r >> 16);
}

__device__ __forceinline__ float tanh_fast(float x) {
    x = fminf(fmaxf(x, -10.f), 10.f);                  // avoid inf*0
    float e = __builtin_amdgcn_exp2f(x * 2.885390082f); // e^(2x)
    return (e - 1.0f) * __builtin_amdgcn_rcpf(e + 1.0f);
}

// ---------------------------------------------------------------------------
// Kernel 1: W1 [D][U] f32 -> W1T_sw bf16, tiled layout:
//   tile ti = (nt*16 + kt), nt = u>>7, kt = d>>5  (8 KB per tile)
//   within tile: [kc(4)][n(128)][e(8)]  : kc = (d&31)>>3, n = u&127, e = d&7
// Staging in k_score is then a linear 8 KB copy and fragment reads are dense.
// ---------------------------------------------------------------------------
__global__ void k_w1t(const float* __restrict__ W1, unsigned short* __restrict__ W1T) {
    int gid = blockIdx.x * 256 + threadIdx.x;   // 32768 threads
    int u  = gid & 511;
    int dc = gid >> 9;                          // d-chunk of 8, 0..63
    int d0 = dc * 8;
    u16x8 pk;
    #pragma unroll
    for (int e = 0; e < 8; ++e)
        pk[e] = f2bf(W1[(size_t)(d0 + e) * UU + u]);
    int nt = u >> 7, n = u & 127;
    int kt = dc >> 2, kc = dc & 3;
    size_t off = ((size_t)(nt * 16 + kt) * 8192 + kc * 2048 + n * 16) / 2;
    *(u16x8*)(W1T + off) = pk;
}

// ---------------------------------------------------------------------------
// Kernel 2: phc[b][u] = b1[u] + b2[u] + hidden[b,:] @ W2[:,u]
// ---------------------------------------------------------------------------
__global__ void k_phc(const float* __restrict__ hidden, const float* __restrict__ W2,
                      const float* __restrict__ b1, const float* __restrict__ b2,
                      float* __restrict__ phc) {
    const int b = blockIdx.x;
    const int u = threadIdx.x;         // 512 threads
    const float* h = hidden + (size_t)b * DD;
    float acc = b1[u] + b2[u];
    #pragma unroll 8
    for (int d = 0; d < DD; ++d)
        acc += h[d] * W2[(size_t)d * UU + u];
    phc[(size_t)b * UU + u] = acc;
}

// ---------------------------------------------------------------------------
// Kernel 3: partial-score GEMM, m97 structure.
// Tile BM=128 x BN=128 x BK=32, 256 threads = 4 waves (2x2 of 64x64).
// Grid 4096 = (gx 0..1023) x (gy 0..3); XCD-swizzled so the 4 gy-siblings of
// each gx run temporally close on the SAME XCD (A-tile L2 reuse).
// Writes 128 m-partials to part[gy][m].
// ---------------------------------------------------------------------------
__launch_bounds__(256, 3)
__global__ void k_score(const float* __restrict__ feat,
                        const unsigned short* __restrict__ W1T,
                        const float* __restrict__ phc,
                        const float* __restrict__ V,
                        float* __restrict__ part) {
    __shared__ float sA[128 * 32];            // [m][32k] f32, XOR-swizzled chunks, 16 KB
    __shared__ unsigned short sB[4096];       // [kc][n][8] bf16, 8 KB
    __shared__ float sRed[4][64];

    const int tid  = threadIdx.x;
    const int lane = tid & 63;
    const int w    = tid >> 6;                // wave 0..3
    const int wr   = w >> 1, wc = w & 1;

    // XCD-aware decomposition
    const int rb  = blockIdx.x;
    const int xcd = rb & 7;
    const int uu  = rb >> 3;
    const int gy  = uu & 3;
    const int gx  = xcd * 128 + (uu >> 2);
    const int m0  = gx * 128;
    const int b   = m0 >> 11;

    f32x4 acc[4][4];
    #pragma unroll
    for (int i = 0; i < 4; ++i)
        #pragma unroll
        for (int j = 0; j < 4; ++j)
            acc[i][j] = (f32x4){0.f, 0.f, 0.f, 0.f};

    const char* fbase0 = (const char*)feat + (size_t)m0 * 2048;
    const char* bslab0 = (const char*)W1T + (size_t)gy * 16 * 8192;

    for (int kt = 0; kt < 16; ++kt) {
        // --- stage B: linear 8 KB copy (layout pre-swizzled by k_w1t) ---
        const char* bslab = bslab0 + kt * 8192;
        #pragma unroll
        for (int p = 0; p < 2; ++p) {
            int s = p * 256 + tid;
            const char* src = bslab + s * 16;
            char* dst = (char*)sB + (size_t)(p * 256 + (tid & ~63)) * 16;
            __builtin_amdgcn_global_load_lds((const GLOBAL_AS u32*)src, (LDS_AS u32*)dst, 16, 0, 0);
        }
        // --- stage A: 16 KB f32, source-swizzled chunk permutation ---
        const char* fbase = fbase0 + kt * 128;
        #pragma unroll
        for (int j = 0; j < 4; ++j) {
            int s = j * 256 + tid;
            int row = s >> 3;
            int cpos = s & 7;
            int c = cpos ^ (row & 7);
            const char* src = fbase + (size_t)row * 2048 + c * 16;
            char* dst = (char*)sA + (size_t)(j * 256 + (tid & ~63)) * 16;
            __builtin_amdgcn_global_load_lds((const GLOBAL_AS u32*)src, (LDS_AS u32*)dst, 16, 0, 0);
        }
        __syncthreads();

        // --- fragments ---
        const int kc = lane >> 4;
        bf16x8 bfr[4];
        #pragma unroll
        for (int ns = 0; ns < 4; ++ns) {
            int n = wc * 64 + ns * 16 + (lane & 15);
            bfr[ns] = *(const bf16x8*)((const char*)sB + kc * 2048 + n * 16);
        }
        #pragma unroll
        for (int ms = 0; ms < 4; ++ms) {
            int m = wr * 64 + ms * 16 + (lane & 15);
            int c0 = (2 * kc) ^ (m & 7);
            int c1 = (2 * kc + 1) ^ (m & 7);
            f32x4 a0 = *(const f32x4*)((const char*)sA + m * 128 + c0 * 16);
            f32x4 a1 = *(const f32x4*)((const char*)sA + m * 128 + c1 * 16);
            bf16x8 af;
            #pragma unroll
            for (int j = 0; j < 4; ++j) { af[j] = (__bf16)a0[j]; af[4 + j] = (__bf16)a1[j]; }
            #pragma unroll
            for (int ns = 0; ns < 4; ++ns)
                acc[ms][ns] = __builtin_amdgcn_mfma_f32_16x16x32_bf16(af, bfr[ns], acc[ms][ns], 0, 0, 0);
        }
        __syncthreads();
    }

    // --- epilogue: partial score over this block's 128 n-cols ---
    float pc[4], vv[4];
    #pragma unroll
    for (int ns = 0; ns < 4; ++ns) {
        int ug = gy * 128 + wc * 64 + ns * 16 + (lane & 15);
        pc[ns] = phc[(size_t)b * UU + ug];
        vv[ns] = V[ug];
    }
    float pr[4][4];
    #pragma unroll
    for (int ms = 0; ms < 4; ++ms)
        #pragma unroll
        for (int rg = 0; rg < 4; ++rg) {
            float s = 0.f;
            #pragma unroll
            for (int ns = 0; ns < 4; ++ns)
                s += tanh_fast(acc[ms][ns][rg] + pc[ns]) * vv[ns];
            pr[ms][rg] = s;
        }
    #pragma unroll
    for (int off = 1; off < 16; off <<= 1)
        #pragma unroll
        for (int ms = 0; ms < 4; ++ms)
            #pragma unroll
            for (int rg = 0; rg < 4; ++rg)
                pr[ms][rg] += __shfl_xor(pr[ms][rg], off, 64);
    if ((lane & 15) == 0) {
        int rowg = lane >> 4;
        #pragma unroll
        for (int ms = 0; ms < 4; ++ms)
            #pragma unroll
            for (int rg = 0; rg < 4; ++rg)
                sRed[w][ms * 16 + rowg * 4 + rg] = pr[ms][rg];
    }
    __syncthreads();
    if (tid < 128) {
        int wrx = tid >> 6, ml = tid & 63;
        float v = sRed[2 * wrx][ml] + sRed[2 * wrx + 1][ml];
        part[(size_t)gy * MM + m0 + tid] = v;
    }
}

// ---------------------------------------------------------------------------
// Kernel 4: sum 4 partials -> softmax over T -> d_out attn region.
// ---------------------------------------------------------------------------
__global__ void k_softmax(const float* __restrict__ part, float* __restrict__ dout) {
    const int b = blockIdx.x, tid = threadIdx.x;   // 256 threads
    float* sc = dout + ATTN_OFF + (size_t)b * TT;
    float v[8];
    float mx = -3.4e38f;
    #pragma unroll
    for (int i = 0; i < 8; ++i) {
        int t = tid + 256 * i;
        size_t idx = (size_t)b * TT + t;
        v[i] = part[idx] + part[MM + idx] + part[2 * MM + idx] + part[3 * MM + idx];
        mx = fmaxf(mx, v[i]);
    }
    __shared__ float red[256];
    red[tid] = mx; __syncthreads();
    for (int s = 128; s >= 1; s >>= 1) {
        if (tid < s) red[tid] = fmaxf(red[tid], red[tid + s]);
        __syncthreads();
    }
    mx = red[0]; __syncthreads();
    float sum = 0.f;
    #pragma unroll
    for (int i = 0; i < 8; ++i) { v[i] = __expf(v[i] - mx); sum += v[i]; }
    red[tid] = sum; __syncthreads();
    for (int s = 128; s >= 1; s >>= 1) {
        if (tid < s) red[tid] += red[tid + s];
        __syncthreads();
    }
    float inv = 1.0f / red[0];
    #pragma unroll
    for (int i = 0; i < 8; ++i) sc[tid + 256 * i] = v[i] * inv;
}

// ---------------------------------------------------------------------------
// Kernel 5: context[b][d] = sum_t w[b][t] * feat[b][t][d]
// grid (64, 8); 256 threads = 16 d-quads (float4) x 16 t-subgroups.
// ---------------------------------------------------------------------------
__global__ void k_context(const float* __restrict__ feat, float* __restrict__ dout) {
    const int b = blockIdx.x, dc = blockIdx.y;
    const int dq = threadIdx.x & 15;          // float4 lane
    const int ty = threadIdx.x >> 4;          // 0..15
    const int d = dc * 64 + dq * 4;
    const float* wgt = dout + ATTN_OFF + (size_t)b * TT;
    const float* f = feat + (size_t)b * TT * DD + d;
    float4 acc = {0.f, 0.f, 0.f, 0.f};
    #pragma unroll 4
    for (int i = 0; i < TT / 16; ++i) {
        int t = i * 16 + ty;
        float wv = wgt[t];
        float4 fv = *(const float4*)(f + (size_t)t * DD);
        acc.x += wv * fv.x; acc.y += wv * fv.y;
        acc.z += wv * fv.z; acc.w += wv * fv.w;
    }
    __shared__ float4 red[16][16];
    red[ty][dq] = acc; __syncthreads();
    if (ty == 0) {
        float4 s = red[0][dq];
        #pragma unroll
        for (int k = 1; k < 16; ++k) {
            float4 r = red[k][dq];
            s.x += r.x; s.y += r.y; s.z += r.z; s.w += r.w;
        }
        *(float4*)(dout + (size_t)b * DD + d) = s;
    }
}

// ---------------------------------------------------------------------------
extern "C" void kernel_launch(void* const* d_in, const int* in_sizes, int n_in,
                              void* d_out, int out_size, void* d_ws, size_t ws_size,
                              hipStream_t stream) {
    (void)in_sizes; (void)n_in; (void)out_size; (void)ws_size;
    const float* feat   = (const float*)d_in[0];
    const float* hidden = (const float*)d_in[1];
    const float* W1     = (const float*)d_in[2];
    const float* b1     = (const float*)d_in[3];
    const float* W2     = (const float*)d_in[4];
    const float* b2     = (const float*)d_in[5];
    const float* V      = (const float*)d_in[6];
    // d_in[7] = bV : softmax-invariant constant, unused.

    // ws layout: [0,512K) W1T_sw bf16; [512K,640K) phc f32; [640K,640K+2M) partials
    unsigned short* W1T = (unsigned short*)d_ws;
    float* phc  = (float*)((char*)d_ws + 512 * 1024);
    float* part = (float*)((char*)d_ws + 640 * 1024);
    float* out  = (float*)d_out;

    hipLaunchKernelGGL(k_w1t,     dim3(128),    dim3(256), 0, stream, W1, W1T);
    hipLaunchKernelGGL(k_phc,     dim3(64),     dim3(512), 0, stream, hidden, W2, b1, b2, phc);
    hipLaunchKernelGGL(k_score,   dim3(4096),   dim3(256), 0, stream, feat, W1T, phc, V, part);
    hipLaunchKernelGGL(k_softmax, dim3(64),     dim3(256), 0, stream, part, out);
    hipLaunchKernelGGL(k_context, dim3(64, 8),  dim3(256), 0, stream, feat, out);
}

// Round 3
// 195.043 us; speedup vs baseline: 1.6635x; 1.0047x over previous
//
#include <hip/hip_runtime.h>
#include <hip/hip_bf16.h>

// Problem constants (B=64, T=2048, D=512, U=512)
#define BB 64
#define TT 2048
#define DD 512
#define UU 512
#define MM (BB * TT)                 // 131072 rows
#define CTX_ELEMS (BB * DD)          // context region of d_out
#define ATTN_OFF  CTX_ELEMS          // attention region offset in d_out

typedef __bf16 bf16x8 __attribute__((ext_vector_type(8)));
typedef float  f32x4  __attribute__((ext_vector_type(4)));
typedef unsigned short u16x8 __attribute__((ext_vector_type(8)));
typedef unsigned int u32;

#define GLOBAL_AS __attribute__((address_space(1)))
#define LDS_AS    __attribute__((address_space(3)))

__device__ __forceinline__ unsigned short f2bf(float f) {
    union { float f; unsigned u; } x; x.f = f;
    unsigned r = x.u + 0x7fffu + ((x.u >> 16) & 1u);   // RNE
    return (unsigned short)(r >> 16);
}

__device__ __forceinline__ float tanh_fast(float x) {
    x = fminf(fmaxf(x, -10.f), 10.f);                  // avoid inf*0
    float e = __builtin_amdgcn_exp2f(x * 2.885390082f); // e^(2x)
    return (e - 1.0f) * __builtin_amdgcn_rcpf(e + 1.0f);
}

// ---------------------------------------------------------------------------
// Kernel 1: W1 [D][U] f32 -> W1T bf16, tiled layout:
//   tile ti = (nt*16 + kt), nt = u>>7, kt = d>>5  (8 KB per tile)
//   within tile: [kc(4)][n(128)][e(8)] : kc = (d&31)>>3, n = u&127, e = d&7
// ---------------------------------------------------------------------------
__global__ void k_w1t(const float* __restrict__ W1, unsigned short* __restrict__ W1T) {
    int gid = blockIdx.x * 256 + threadIdx.x;   // 32768 threads
    int u  = gid & 511;
    int dc = gid >> 9;                          // d-chunk of 8, 0..63
    int d0 = dc * 8;
    u16x8 pk;
    #pragma unroll
    for (int e = 0; e < 8; ++e)
        pk[e] = f2bf(W1[(size_t)(d0 + e) * UU + u]);
    int nt = u >> 7, n = u & 127;
    int kt = dc >> 2, kc = dc & 3;
    size_t off = ((size_t)(nt * 16 + kt) * 8192 + kc * 2048 + n * 16) / 2;
    *(u16x8*)(W1T + off) = pk;
}

// ---------------------------------------------------------------------------
// Kernel 2: phc[b][u] = b1[u] + b2[u] + hidden[b,:] @ W2[:,u]
// ---------------------------------------------------------------------------
__global__ void k_phc(const float* __restrict__ hidden, const float* __restrict__ W2,
                      const float* __restrict__ b1, const float* __restrict__ b2,
                      float* __restrict__ phc) {
    const int b = blockIdx.x;
    const int u = threadIdx.x;         // 512 threads
    const float* h = hidden + (size_t)b * DD;
    float acc = b1[u] + b2[u];
    #pragma unroll 8
    for (int d = 0; d < DD; ++d)
        acc += h[d] * W2[(size_t)d * UU + u];
    phc[(size_t)b * UU + u] = acc;
}

// ---------------------------------------------------------------------------
// Kernel 3: partial-score GEMM, double-buffered 2-phase (T3-min + T14).
// Tile BM=128 x BN=128 x BK=32, 256 threads = 4 waves (2x2 of 64x64).
// A (feat f32) is reg-staged with f32->bf16 conversion at stage time;
// both LDS tiles are [kc(4)][row(128)][8e] bf16 -> dense b128 frag reads.
// Grid 4096 = (gx 0..1023) x (gy 0..3), XCD-swizzled for A-tile L2 reuse.
// ---------------------------------------------------------------------------
__launch_bounds__(256, 4)
__global__ void k_score(const float* __restrict__ feat,
                        const unsigned short* __restrict__ W1T,
                        const float* __restrict__ phc,
                        const float* __restrict__ V,
                        float* __restrict__ part) {
    __shared__ __align__(16) unsigned short sA[2][4096];  // 8 KB each buf
    __shared__ __align__(16) unsigned short sB[2][4096];
    __shared__ float sRed[4][64];

    const int tid  = threadIdx.x;
    const int lane = tid & 63;
    const int w    = tid >> 6;                // wave 0..3
    const int wr   = w >> 1, wc = w & 1;

    // XCD-aware decomposition
    const int rb  = blockIdx.x;
    const int xcd = rb & 7;
    const int uu  = rb >> 3;
    const int gy  = uu & 3;
    const int gx  = xcd * 128 + (uu >> 2);
    const int m0  = gx * 128;
    const int b   = m0 >> 11;

    const char* bslab0 = (const char*)W1T + (size_t)gy * 16 * 8192;
    const char* fbase0 = (const char*)feat + (size_t)m0 * 2048;

    const int r = tid >> 1;                   // staging row 0..127
    const int h = tid & 1;                    // k-half (16 floats)
    const char* fA = fbase0 + (size_t)r * 2048 + h * 64;

    f32x4 areg0, areg1, areg2, areg3;

    #define STAGE_B(buf, kt_) {                                                   \
        const char* bs = bslab0 + (kt_) * 8192;                                   \
        _Pragma("unroll")                                                         \
        for (int p = 0; p < 2; ++p) {                                             \
            const char* src = bs + (size_t)(p * 256 + tid) * 16;                  \
            char* dst = (char*)&sB[buf][0] + (size_t)(p * 256 + (tid & ~63)) * 16;\
            __builtin_amdgcn_global_load_lds((const GLOBAL_AS u32*)src,           \
                                             (LDS_AS u32*)dst, 16, 0, 0);         \
        }                                                                         \
    }
    #define LOAD_A(kt_) {                                                         \
        const char* s_ = fA + (kt_) * 128;                                        \
        areg0 = *(const f32x4*)(s_);                                              \
        areg1 = *(const f32x4*)(s_ + 16);                                         \
        areg2 = *(const f32x4*)(s_ + 32);                                         \
        areg3 = *(const f32x4*)(s_ + 48);                                         \
    }
    #define WRITE_A(buf) {                                                        \
        bf16x8 p0, p1;                                                            \
        _Pragma("unroll")                                                         \
        for (int j = 0; j < 4; ++j) {                                             \
            p0[j] = (__bf16)areg0[j]; p0[4 + j] = (__bf16)areg1[j];               \
            p1[j] = (__bf16)areg2[j]; p1[4 + j] = (__bf16)areg3[j];               \
        }                                                                         \
        *(bf16x8*)((char*)&sA[buf][0] + (2 * h) * 2048 + r * 16) = p0;            \
        *(bf16x8*)((char*)&sA[buf][0] + (2 * h + 1) * 2048 + r * 16) = p1;        \
    }

    f32x4 acc[4][4];
    #pragma unroll
    for (int i = 0; i < 4; ++i)
        #pragma unroll
        for (int j = 0; j < 4; ++j)
            acc[i][j] = (f32x4){0.f, 0.f, 0.f, 0.f};

    // prologue: fill buffer 0
    STAGE_B(0, 0);
    LOAD_A(0);
    WRITE_A(0);            // compiler inserts vmcnt wait for areg deps
    __syncthreads();       // drains vmcnt (gload_lds) + lgkmcnt (ds_write)

    for (int kt = 0; kt < 16; ++kt) {
        const int cur = kt & 1;
        if (kt < 15) {              // issue next tile's loads EARLY
            STAGE_B(cur ^ 1, kt + 1);
            LOAD_A(kt + 1);
        }
        // fragments from current buffer (dense b128, no converts)
        const int kc = lane >> 4;
        bf16x8 bfr[4], af[4];
        #pragma unroll
        for (int ns = 0; ns < 4; ++ns)
            bfr[ns] = *(const bf16x8*)((const char*)&sB[cur][0] + kc * 2048 +
                                       (wc * 64 + ns * 16 + (lane & 15)) * 16);
        #pragma unroll
        for (int ms = 0; ms < 4; ++ms)
            af[ms] = *(const bf16x8*)((const char*)&sA[cur][0] + kc * 2048 +
                                      (wr * 64 + ms * 16 + (lane & 15)) * 16);
        __builtin_amdgcn_s_setprio(1);
        #pragma unroll
        for (int ms = 0; ms < 4; ++ms)
            #pragma unroll
            for (int ns = 0; ns < 4; ++ns)
                acc[ms][ns] = __builtin_amdgcn_mfma_f32_16x16x32_bf16(af[ms], bfr[ns], acc[ms][ns], 0, 0, 0);
        __builtin_amdgcn_s_setprio(0);
        if (kt < 15) WRITE_A(cur ^ 1);   // write-late into the other buffer
        __syncthreads();
    }
    #undef STAGE_B
    #undef LOAD_A
    #undef WRITE_A

    // --- epilogue: partial score over this block's 128 n-cols ---
    float pc[4], vv[4];
    #pragma unroll
    for (int ns = 0; ns < 4; ++ns) {
        int ug = gy * 128 + wc * 64 + ns * 16 + (lane & 15);
        pc[ns] = phc[(size_t)b * UU + ug];
        vv[ns] = V[ug];
    }
    float pr[4][4];
    #pragma unroll
    for (int ms = 0; ms < 4; ++ms)
        #pragma unroll
        for (int rg = 0; rg < 4; ++rg) {
            float s = 0.f;
            #pragma unroll
            for (int ns = 0; ns < 4; ++ns)
                s += tanh_fast(acc[ms][ns][rg] + pc[ns]) * vv[ns];
            pr[ms][rg] = s;
        }
    #pragma unroll
    for (int off = 1; off < 16; off <<= 1)
        #pragma unroll
        for (int ms = 0; ms < 4; ++ms)
            #pragma unroll
            for (int rg = 0; rg < 4; ++rg)
                pr[ms][rg] += __shfl_xor(pr[ms][rg], off, 64);
    if ((lane & 15) == 0) {
        int rowg = lane >> 4;
        #pragma unroll
        for (int ms = 0; ms < 4; ++ms)
            #pragma unroll
            for (int rg = 0; rg < 4; ++rg)
                sRed[w][ms * 16 + rowg * 4 + rg] = pr[ms][rg];
    }
    __syncthreads();
    if (tid < 128) {
        int wrx = tid >> 6, ml = tid & 63;
        float v = sRed[2 * wrx][ml] + sRed[2 * wrx + 1][ml];
        part[(size_t)gy * MM + m0 + tid] = v;
    }
}

// ---------------------------------------------------------------------------
// Kernel 4: sum 4 partials -> softmax over T -> d_out attn region.
// ---------------------------------------------------------------------------
__global__ void k_softmax(const float* __restrict__ part, float* __restrict__ dout) {
    const int b = blockIdx.x, tid = threadIdx.x;   // 256 threads
    float* sc = dout + ATTN_OFF + (size_t)b * TT;
    float v[8];
    float mx = -3.4e38f;
    #pragma unroll
    for (int i = 0; i < 8; ++i) {
        int t = tid + 256 * i;
        size_t idx = (size_t)b * TT + t;
        v[i] = part[idx] + part[MM + idx] + part[2 * MM + idx] + part[3 * MM + idx];
        mx = fmaxf(mx, v[i]);
    }
    __shared__ float red[256];
    red[tid] = mx; __syncthreads();
    for (int s = 128; s >= 1; s >>= 1) {
        if (tid < s) red[tid] = fmaxf(red[tid], red[tid + s]);
        __syncthreads();
    }
    mx = red[0]; __syncthreads();
    float sum = 0.f;
    #pragma unroll
    for (int i = 0; i < 8; ++i) { v[i] = __expf(v[i] - mx); sum += v[i]; }
    red[tid] = sum; __syncthreads();
    for (int s = 128; s >= 1; s >>= 1) {
        if (tid < s) red[tid] += red[tid + s];
        __syncthreads();
    }
    float inv = 1.0f / red[0];
    #pragma unroll
    for (int i = 0; i < 8; ++i) sc[tid + 256 * i] = v[i] * inv;
}

// ---------------------------------------------------------------------------
// Kernel 5: context[b][d] = sum_t w[b][t] * feat[b][t][d]
// grid (64, 8); 256 threads = 16 d-quads (float4) x 16 t-subgroups.
// ---------------------------------------------------------------------------
__global__ void k_context(const float* __restrict__ feat, float* __restrict__ dout) {
    const int b = blockIdx.x, dc = blockIdx.y;
    const int dq = threadIdx.x & 15;          // float4 lane
    const int ty = threadIdx.x >> 4;          // 0..15
    const int d = dc * 64 + dq * 4;
    const float* wgt = dout + ATTN_OFF + (size_t)b * TT;
    const float* f = feat + (size_t)b * TT * DD + d;
    float4 acc = {0.f, 0.f, 0.f, 0.f};
    #pragma unroll 4
    for (int i = 0; i < TT / 16; ++i) {
        int t = i * 16 + ty;
        float wv = wgt[t];
        float4 fv = *(const float4*)(f + (size_t)t * DD);
        acc.x += wv * fv.x; acc.y += wv * fv.y;
        acc.z += wv * fv.z; acc.w += wv * fv.w;
    }
    __shared__ float4 red[16][16];
    red[ty][dq] = acc; __syncthreads();
    if (ty == 0) {
        float4 s = red[0][dq];
        #pragma unroll
        for (int k = 1; k < 16; ++k) {
            float4 r = red[k][dq];
            s.x += r.x; s.y += r.y; s.z += r.z; s.w += r.w;
        }
        *(float4*)(dout + (size_t)b * DD + d) = s;
    }
}

// ---------------------------------------------------------------------------
extern "C" void kernel_launch(void* const* d_in, const int* in_sizes, int n_in,
                              void* d_out, int out_size, void* d_ws, size_t ws_size,
                              hipStream_t stream) {
    (void)in_sizes; (void)n_in; (void)out_size; (void)ws_size;
    const float* feat   = (const float*)d_in[0];
    const float* hidden = (const float*)d_in[1];
    const float* W1     = (const float*)d_in[2];
    const float* b1     = (const float*)d_in[3];
    const float* W2     = (const float*)d_in[4];
    const float* b2     = (const float*)d_in[5];
    const float* V      = (const float*)d_in[6];
    // d_in[7] = bV : softmax-invariant constant, unused.

    // ws layout: [0,512K) W1T bf16; [512K,640K) phc f32; [640K,640K+2M) partials
    unsigned short* W1T = (unsigned short*)d_ws;
    float* phc  = (float*)((char*)d_ws + 512 * 1024);
    float* part = (float*)((char*)d_ws + 640 * 1024);
    float* out  = (float*)d_out;

    hipLaunchKernelGGL(k_w1t,     dim3(128),    dim3(256), 0, stream, W1, W1T);
    hipLaunchKernelGGL(k_phc,     dim3(64),     dim3(512), 0, stream, hidden, W2, b1, b2, phc);
    hipLaunchKernelGGL(k_score,   dim3(4096),   dim3(256), 0, stream, feat, W1T, phc, V, part);
    hipLaunchKernelGGL(k_softmax, dim3(64),     dim3(256), 0, stream, part, out);
    hipLaunchKernelGGL(k_context, dim3(64, 8),  dim3(256), 0, stream, feat, out);
}